// Round 7
// baseline (128.473 us; speedup 1.0000x reference)
//
#include <hip/hip_runtime.h>
#include <math.h>

#define SQ 512
#define NU_C 0.5f

typedef float fvec4 __attribute__((ext_vector_type(4)));

// output offsets (floats)
#define EST_OFF   0
#define OUT_OFF   131072
#define QIJ_OFF   262144
#define XHAT_OFF  33816576
#define LAM_OFF   100925440

// workspace offsets (floats), all [b][s][d][2] interleaved
#define WQ_OFF  0
#define WK_OFF  131072
#define WV_OFF  262144
#define WEV_OFF 393216

// ---------------------------------------------------------------------------
// Kernel 1: complex projections Q,K,V = cmm(W, b, X)  ->  ws [b][s][d][2]
// grid = 192: p (0..2) x b (0..1) x s-tile (0..31)
// ---------------------------------------------------------------------------
__global__ __launch_bounds__(256) void proj_kernel(
    const float* __restrict__ Xq, const float* __restrict__ Xk, const float* __restrict__ Xv,
    const float* __restrict__ Wq, const float* __restrict__ Wk, const float* __restrict__ Wv,
    const float* __restrict__ bq, const float* __restrict__ bk, const float* __restrict__ bv,
    float* __restrict__ ws)
{
    const int TILE = 16;
    __shared__ float WT0[64 * 65];
    __shared__ float WT1[64 * 65];
    __shared__ float XT[2 * TILE * 64];

    int t   = threadIdx.x;
    int blk = blockIdx.x;            // 192 blocks
    int p   = blk >> 6;              // 0..2
    int sub = blk & 63;
    int b   = sub >> 5;
    int s0  = (sub & 31) * TILE;

    const float* Xs[3]   = {Xq, Xk, Xv};
    const float* Wsrc[3] = {Wq, Wk, Wv};
    const float* bs[3]   = {bq, bk, bv};
    float* dst[3] = {ws + WQ_OFF, ws + WK_OFF, ws + WV_OFF};

    const float* W = Wsrc[p];
    for (int it = 0; it < 16; ++it) {
        int e = it * 256 + t;        // 0..4095
        int dd = e >> 6, hw = e & 63;
        WT0[hw * 65 + dd] = W[e];
        WT1[hw * 65 + dd] = W[4096 + e];
    }
    const float* X = Xs[p];
    for (int it = 0; it < (2 * TILE * 64) / 256; ++it) {
        int e = it * 256 + t;
        int ri = e >> 10;            // TILE*64 = 1024
        int sl = (e >> 6) & (TILE - 1);
        int hw = e & 63;
        XT[e] = X[(size_t)(b * 2 + ri) * (SQ * 64) + (size_t)(s0 + sl) * 64 + hw];
    }
    __syncthreads();

    int dd = t & 63, sg = t >> 6;
    float b0 = bs[p][dd], b1 = bs[p][64 + dd];
    for (int sl = sg; sl < TILE; sl += 4) {
        float ar = b0, ai = b1;
        for (int h = 0; h < 64; ++h) {
            float xr = XT[sl * 64 + h];
            float xi = XT[TILE * 64 + sl * 64 + h];
            float w0 = WT0[h * 65 + dd];
            float w1 = WT1[h * 65 + dd];
            ar += xr * w0 - xi * w1;
            ai += xr * w1 + xi * w0;
        }
        float2 o; o.x = ar; o.y = ai;
        *(float2*)&dst[p][(size_t)((b * SQ + s0 + sl) * 64 + dd) * 2] = o;
    }
}

// ---------------------------------------------------------------------------
// Kernel 2: main attention. ONE row per block, 8 waves (512 thr), lane=d.
// Each wave owns a CONTIGUOUS j-chunk -> sequential HBM write streams.
// Regular (cached) stores -> L2 write-combining. Paired block->row mapping.
// ---------------------------------------------------------------------------
__global__ __launch_bounds__(512, 4) void main_kernel(
    const float* __restrict__ tm,     // (B, S+1)
    const float* __restrict__ lam1,   // (2,32)
    const float* __restrict__ lOm, const float* __restrict__ lOm0,
    const float* __restrict__ lGam, const float* __restrict__ lC,
    const float* __restrict__ ws,
    float* __restrict__ evw,          // est_v out [b][s][d][2]
    float* __restrict__ out)
{
    __shared__ float t_lds[SQ];
    __shared__ float rden_l[2][SQ];
    __shared__ float red[8][2][3][64];

    int tid  = threadIdx.x;
    int lane = tid & 63;
    int wave = tid >> 6;          // 0..7
    int d = lane;
    int bx = (int)blockIdx.x;
    int i = (bx < 256) ? (SQ - 1 - bx) : (bx - 256);   // pair heavy+light per CU

    float l0 = lam1[d & 31];
    float l1 = lam1[32 + (d & 31)];
    float realv = -fabsf(l0);
    float imagv = (d < 32) ? l1 : -l1;
    float Om  = lOm[d]  * lOm[d];
    float Om0 = lOm0[d] * lOm0[d];
    float Gam = lGam[d] * lGam[d];
    float C   = lC[d];
    float C2  = C * C;
    float r2r = 1.0f / (2.0f * realv);
    float pA  = C2 * (Om0 + Om * r2r);
    float pB  = Gam - C2 * Om * r2r;

    for (int q = tid; q < SQ; q += 512) t_lds[q] = tm[q];  // t_measure_all[0,:-1]
    __syncthreads();

    const float2* Kw = (const float2*)(ws + WK_OFF);
    const float2* Vw = (const float2*)(ws + WV_OFF);
    const float2* Qw = (const float2*)(ws + WQ_OFF);

    float ti = t_lds[i];
    float2 q0 = Qw[(0 * SQ + i) * 64 + d];
    float2 q1 = Qw[(1 * SQ + i) * 64 + d];
    float sA0 = 0, sXr0 = 0, sXi0 = 0, sA1 = 0, sXr1 = 0, sXi1 = 0;

    float* xh0 = out + XHAT_OFF + (size_t)(0 * SQ + i) * SQ * 64;
    float* xh1 = out + XHAT_OFF + (size_t)(1 * SQ + i) * SQ * 64;
    float* xh2 = out + XHAT_OFF + (size_t)(2 * SQ + i) * SQ * 64;
    float* xh3 = out + XHAT_OFF + (size_t)(3 * SQ + i) * SQ * 64;
    float* qij0 = out + QIJ_OFF + (size_t)(0 * SQ + i) * SQ * 64;
    float* qij1 = out + QIJ_OFF + (size_t)(1 * SQ + i) * SQ * 64;

    // contiguous j-chunk per wave
    int per = (i + 8) >> 3;               // ceil((i+1)/8)
    int jlo = wave * per;
    int jhi = (jlo + per <= i + 1) ? (jlo + per) : (i + 1);

    #pragma unroll 2
    for (int j = jlo; j < jhi; ++j) {
        float dt = ti - t_lds[j];
        float e = __expf(realv * dt);
        float sph, cph;
        __sincosf(imagv * dt, &sph, &cph);
        float ar = e * cph, ai = e * sph;
        float e2 = e * e;
        float P = 1.0f / fmaf(e2, pA, pB);

        float2 k0 = Kw[(0 * SQ + j) * 64 + d];
        float2 v0 = Vw[(0 * SQ + j) * 64 + d];
        float2 k1 = Kw[(1 * SQ + j) * 64 + d];
        float2 v1 = Vw[(1 * SQ + j) * 64 + d];

        float xr0 = ar * v0.x - ai * v0.y, xi0 = ar * v0.y + ai * v0.x;
        float xr1 = ar * v1.x - ai * v1.y, xi1 = ar * v1.y + ai * v1.x;
        float khr0 = ar * k0.x - ai * k0.y, khi0 = ar * k0.y + ai * k0.x;
        float khr1 = ar * k1.x - ai * k1.y, khi1 = ar * k1.y + ai * k1.x;
        float Rr0 = q0.x - C * khr0, Ri0 = q0.y - C * khi0;
        float Rr1 = q1.x - C * khr1, Ri1 = q1.y - C * khi1;
        float m0 = P * fmaf(Rr0, Rr0, Ri0 * Ri0);
        float m1 = P * fmaf(Rr1, Rr1, Ri1 * Ri1);
        #pragma unroll
        for (int off = 32; off > 0; off >>= 1) {
            m0 += __shfl_xor(m0, off);
            m1 += __shfl_xor(m1, off);
        }
        float rd0 = 1.0f / (1.0f + NU_C * m0);
        float rd1 = 1.0f / (1.0f + NU_C * m1);
        float A0 = P * rd0, A1 = P * rd1;
        sA0 += A0; sXr0 = fmaf(A0, xr0, sXr0); sXi0 = fmaf(A0, xi0, sXi0);
        sA1 += A1; sXr1 = fmaf(A1, xr1, sXr1); sXi1 = fmaf(A1, xi1, sXi1);

        size_t jb = (size_t)j * 64 + d;
        xh0[jb] = xr0;
        xh1[jb] = xi0;
        xh2[jb] = xr1;
        xh3[jb] = xi1;
        if (lane == 0) { rden_l[0][j] = rd0; rden_l[1][j] = rd1; }
    }
    red[wave][0][0][d] = sA0; red[wave][0][1][d] = sXr0; red[wave][0][2][d] = sXi0;
    red[wave][1][0][d] = sA1; red[wave][1][1][d] = sXr1; red[wave][1][2][d] = sXi1;
    __syncthreads();

    float tA0 = 0, tXr0 = 0, tXi0 = 0, tA1 = 0, tXr1 = 0, tXi1 = 0;
    #pragma unroll
    for (int w = 0; w < 8; ++w) {
        tA0 += red[w][0][0][d]; tXr0 += red[w][0][1][d]; tXi0 += red[w][0][2][d];
        tA1 += red[w][1][0][d]; tXr1 += red[w][1][1][d]; tXi1 += red[w][1][2][d];
    }
    float rs0 = 1.0f / tA0, rs1 = 1.0f / tA1;
    if (wave == 0) {
        float2 ev0; ev0.x = tXr0 * rs0; ev0.y = tXi0 * rs0;
        float2 ev1; ev1.x = tXr1 * rs1; ev1.y = tXi1 * rs1;
        *(float2*)&evw[(size_t)((0 * SQ + i) * 64 + d) * 2] = ev0;
        *(float2*)&evw[(size_t)((1 * SQ + i) * 64 + d) * 2] = ev1;
    }

    // pass 2: Qij = P * rden * rsumA^-1 (contiguous chunks)
    #pragma unroll 2
    for (int j = jlo; j < jhi; ++j) {
        float dt = ti - t_lds[j];
        float e2 = __expf(2.0f * realv * dt);
        float P = 1.0f / fmaf(e2, pA, pB);
        float qv0 = P * rden_l[0][j] * rs0;
        float qv1 = P * rden_l[1][j] * rs1;
        size_t jb = (size_t)j * 64 + d;
        qij0[jb] = qv0;
        qij1[jb] = qv1;
    }

    // zero-fill masked region j in (i, S)
    int nz4 = ((SQ - 1 - i) * 64) >> 2;   // float4 count per region
    if (nz4 > 0) {
        fvec4 z = {0.f, 0.f, 0.f, 0.f};
        size_t zb = (size_t)(i + 1) * 64;
        float* regs[6] = {qij0 + zb, qij1 + zb, xh0 + zb, xh1 + zb, xh2 + zb, xh3 + zb};
        for (int r6 = 0; r6 < 6; ++r6) {
            float* p4 = regs[r6];
            for (int k4 = tid; k4 < nz4; k4 += 512)
                *(fvec4*)(p4 + (size_t)k4 * 4) = z;
        }
    }
}

// ---------------------------------------------------------------------------
// Kernel 3: epilogue. est = cmm(We,be,est_v); pred = cmm(Wp,bp,rot(est_v));
// out = pred + est; lambda output. grid = 128: b x 64 s-tiles of 8.
// ---------------------------------------------------------------------------
__global__ __launch_bounds__(256) void epi_kernel(
    const float* __restrict__ tm,
    const float* __restrict__ lam1,
    const float* __restrict__ We, const float* __restrict__ be,
    const float* __restrict__ Wp, const float* __restrict__ bp,
    const float* __restrict__ evw,
    float* __restrict__ out)
{
    const int TILE = 8;
    __shared__ float WT0[64 * 65];
    __shared__ float WT1[64 * 65];
    __shared__ float EVr[TILE * 64];
    __shared__ float EVi[TILE * 64];
    __shared__ float mr_s[64], mi_s[64];

    int t = threadIdx.x;
    int blk = blockIdx.x;           // 128 blocks: 64 per batch
    int b = blk >> 6;
    int s0 = (blk & 63) * TILE;

    if (blk == 0 && t < 128) {      // lambda output (2,64)
        int dd = t & 63;
        float l0 = lam1[dd & 31];
        float l1 = lam1[32 + (dd & 31)];
        float v = (t < 64) ? -fabsf(l0) : ((dd < 32) ? l1 : -l1);
        out[LAM_OFF + t] = v;
    }
    if (t < 64) {                   // per-batch rotation
        int dd = t;
        float l0 = lam1[dd & 31];
        float l1 = lam1[32 + (dd & 31)];
        float realv = -fabsf(l0);
        float imagv = (dd < 32) ? l1 : -l1;
        float dtl = tm[b * (SQ + 1) + SQ] - tm[b * (SQ + 1) + SQ - 1];
        float e = __expf(realv * dtl);
        float s, c; __sincosf(imagv * dtl, &s, &c);
        mr_s[dd] = e * c; mi_s[dd] = e * s;
    }
    {   // stage est_v tile (contiguous [s][d][2])
        const float* src = evw + (size_t)(b * SQ + s0) * 128;
        for (int it = 0; it < (TILE * 128) / 256; ++it) {
            int e = it * 256 + t;
            float v = src[e];
            int sl = e >> 7, dd = (e >> 1) & 63, ri = e & 1;
            if (ri == 0) EVr[sl * 64 + dd] = v; else EVi[sl * 64 + dd] = v;
        }
    }
    for (int it = 0; it < 16; ++it) {   // stage We^T
        int e = it * 256 + t;
        int hw = e >> 6, dd = e & 63;
        WT0[dd * 65 + hw] = We[e];
        WT1[dd * 65 + hw] = We[4096 + e];
    }
    __syncthreads();

    int h = t & 63, sg = t >> 6;
    float estr[2], esti[2];
    float be0 = be[h], be1 = be[64 + h];
    #pragma unroll
    for (int k = 0; k < 2; ++k) {
        int sl = sg + k * 4;
        float ar = be0, ai = be1;
        for (int dd = 0; dd < 64; ++dd) {
            float er = EVr[sl * 64 + dd], ei = EVi[sl * 64 + dd];
            float w0 = WT0[dd * 65 + h], w1 = WT1[dd * 65 + h];
            ar += er * w0 - ei * w1;
            ai += er * w1 + ei * w0;
        }
        estr[k] = ar; esti[k] = ai;
        out[EST_OFF + (size_t)((b * 2 + 0) * SQ + s0 + sl) * 64 + h] = ar;
        out[EST_OFF + (size_t)((b * 2 + 1) * SQ + s0 + sl) * 64 + h] = ai;
    }
    __syncthreads();
    for (int it = 0; it < 16; ++it) {   // restage Wp^T
        int e = it * 256 + t;
        int hw = e >> 6, dd = e & 63;
        WT0[dd * 65 + hw] = Wp[e];
        WT1[dd * 65 + hw] = Wp[4096 + e];
    }
    __syncthreads();
    float bp0 = bp[h], bp1 = bp[64 + h];
    #pragma unroll
    for (int k = 0; k < 2; ++k) {
        int sl = sg + k * 4;
        float ar = bp0, ai = bp1;
        for (int dd = 0; dd < 64; ++dd) {
            float er = EVr[sl * 64 + dd], ei = EVi[sl * 64 + dd];
            float pr = mr_s[dd] * er - mi_s[dd] * ei;
            float pi = mr_s[dd] * ei + mi_s[dd] * er;
            float w0 = WT0[dd * 65 + h], w1 = WT1[dd * 65 + h];
            ar += pr * w0 - pi * w1;
            ai += pr * w1 + pi * w0;
        }
        out[OUT_OFF + (size_t)((b * 2 + 0) * SQ + s0 + sl) * 64 + h] = ar + estr[k];
        out[OUT_OFF + (size_t)((b * 2 + 1) * SQ + s0 + sl) * 64 + h] = ai + esti[k];
    }
}

// ---------------------------------------------------------------------------
extern "C" void kernel_launch(void* const* d_in, const int* in_sizes, int n_in,
                              void* d_out, int out_size, void* d_ws, size_t ws_size,
                              hipStream_t stream)
{
    const float* Xq   = (const float*)d_in[0];
    const float* Xk   = (const float*)d_in[1];
    const float* Xv   = (const float*)d_in[2];
    const float* tm   = (const float*)d_in[3];
    const float* lam1 = (const float*)d_in[4];
    const float* lOm  = (const float*)d_in[5];
    const float* lOm0 = (const float*)d_in[6];
    const float* lGam = (const float*)d_in[7];
    const float* lC   = (const float*)d_in[8];
    const float* Wq   = (const float*)d_in[9];
    const float* Wk   = (const float*)d_in[10];
    const float* Wv   = (const float*)d_in[11];
    const float* Wp   = (const float*)d_in[12];
    const float* We   = (const float*)d_in[13];
    const float* bq   = (const float*)d_in[14];
    const float* bk   = (const float*)d_in[15];
    const float* bv   = (const float*)d_in[16];
    const float* bp   = (const float*)d_in[17];
    const float* be   = (const float*)d_in[18];
    float* out = (float*)d_out;
    float* ws  = (float*)d_ws;

    proj_kernel<<<192, 256, 0, stream>>>(Xq, Xk, Xv, Wq, Wk, Wv, bq, bk, bv, ws);
    main_kernel<<<512, 512, 0, stream>>>(tm, lam1, lOm, lOm0, lGam, lC, ws, ws + WEV_OFF, out);
    epi_kernel<<<128, 256, 0, stream>>>(tm, lam1, We, be, Wp, bp, ws + WEV_OFF, out);
}

// Round 8
// 112.114 us; speedup vs baseline: 1.1459x; 1.1459x over previous
//
#include <hip/hip_runtime.h>
#include <math.h>

#define SQ 512
#define NU_C 0.5f

typedef float fvec4 __attribute__((ext_vector_type(4)));
typedef float fvec2 __attribute__((ext_vector_type(2)));

// output offsets (floats)
#define EST_OFF   0
#define OUT_OFF   131072
#define QIJ_OFF   262144
#define XHAT_OFF  33816576
#define LAM_OFF   100925440

// workspace offsets (floats), all [b][s][d][2] interleaved
#define WQ_OFF  0
#define WK_OFF  131072
#define WV_OFF  262144
#define WEV_OFF 393216

// ---------------------------------------------------------------------------
// Kernel 1: complex projections Q,K,V = cmm(W, b, X)  ->  ws [b][s][d][2]
// grid = 192: p (0..2) x b (0..1) x s-tile (0..31)
// ---------------------------------------------------------------------------
__global__ __launch_bounds__(256) void proj_kernel(
    const float* __restrict__ Xq, const float* __restrict__ Xk, const float* __restrict__ Xv,
    const float* __restrict__ Wq, const float* __restrict__ Wk, const float* __restrict__ Wv,
    const float* __restrict__ bq, const float* __restrict__ bk, const float* __restrict__ bv,
    float* __restrict__ ws)
{
    const int TILE = 16;
    __shared__ float WT0[64 * 65];
    __shared__ float WT1[64 * 65];
    __shared__ float XT[2 * TILE * 64];

    int t   = threadIdx.x;
    int blk = blockIdx.x;            // 192 blocks
    int p   = blk >> 6;              // 0..2
    int sub = blk & 63;
    int b   = sub >> 5;
    int s0  = (sub & 31) * TILE;

    const float* Xs[3]   = {Xq, Xk, Xv};
    const float* Wsrc[3] = {Wq, Wk, Wv};
    const float* bs[3]   = {bq, bk, bv};
    float* dst[3] = {ws + WQ_OFF, ws + WK_OFF, ws + WV_OFF};

    const float* W = Wsrc[p];
    for (int it = 0; it < 16; ++it) {
        int e = it * 256 + t;        // 0..4095
        int dd = e >> 6, hw = e & 63;
        WT0[hw * 65 + dd] = W[e];
        WT1[hw * 65 + dd] = W[4096 + e];
    }
    const float* X = Xs[p];
    for (int it = 0; it < (2 * TILE * 64) / 256; ++it) {
        int e = it * 256 + t;
        int ri = e >> 10;            // TILE*64 = 1024
        int sl = (e >> 6) & (TILE - 1);
        int hw = e & 63;
        XT[e] = X[(size_t)(b * 2 + ri) * (SQ * 64) + (size_t)(s0 + sl) * 64 + hw];
    }
    __syncthreads();

    int dd = t & 63, sg = t >> 6;
    float b0 = bs[p][dd], b1 = bs[p][64 + dd];
    for (int sl = sg; sl < TILE; sl += 4) {
        float ar = b0, ai = b1;
        for (int h = 0; h < 64; ++h) {
            float xr = XT[sl * 64 + h];
            float xi = XT[TILE * 64 + sl * 64 + h];
            float w0 = WT0[h * 65 + dd];
            float w1 = WT1[h * 65 + dd];
            ar += xr * w0 - xi * w1;
            ai += xr * w1 + xi * w0;
        }
        float2 o; o.x = ar; o.y = ai;
        *(float2*)&dst[p][(size_t)((b * SQ + s0 + sl) * 64 + dd) * 2] = o;
    }
}

// ---------------------------------------------------------------------------
// Kernel 2: main attention. ONE row per block, 8 waves (512 thr).
// LANE-PAIRED: lane q=l&31 covers d=2q,2q+1; half h=l>>5 covers j0+h.
// Wide loads (dwordx4), wide stores (dwordx2 nt, 512B/instr), 5-step
// half-wave butterfly. Strided j (R6 scheme), paired block->row mapping.
// ---------------------------------------------------------------------------
__global__ __launch_bounds__(512, 4) void main_kernel(
    const float* __restrict__ tm,     // (B, S+1)
    const float* __restrict__ lam1,   // (2,32)
    const float* __restrict__ lOm, const float* __restrict__ lOm0,
    const float* __restrict__ lGam, const float* __restrict__ lC,
    const float* __restrict__ ws,
    float* __restrict__ evw,          // est_v out [b][s][d][2]
    float* __restrict__ out)
{
    __shared__ float t_lds[SQ];
    __shared__ float rden_l[2][SQ];
    __shared__ float red[8][2][3][64];
    __shared__ float rs_l[2][64];

    int tid  = threadIdx.x;
    int lane = tid & 63;
    int wave = tid >> 6;          // 0..7
    int q    = lane & 31;
    int h2   = lane >> 5;         // 0/1 -> j0 / j0+1
    int d0   = 2 * q, d1 = 2 * q + 1;
    int bx = (int)blockIdx.x;
    int i = (bx < 256) ? (SQ - 1 - bx) : (bx - 256);   // pair heavy+light per CU

    // per-d params for d0 and d1
    float la0 = lam1[d0 & 31], lb0 = lam1[32 + (d0 & 31)];
    float la1 = lam1[d1 & 31], lb1 = lam1[32 + (d1 & 31)];
    float rv0 = -fabsf(la0),  rv1 = -fabsf(la1);
    float iv0 = (d0 < 32) ? lb0 : -lb0;
    float iv1 = (d1 < 32) ? lb1 : -lb1;
    float Om_0 = lOm[d0] * lOm[d0],   Om_1 = lOm[d1] * lOm[d1];
    float Oo_0 = lOm0[d0] * lOm0[d0], Oo_1 = lOm0[d1] * lOm0[d1];
    float Gm_0 = lGam[d0] * lGam[d0], Gm_1 = lGam[d1] * lGam[d1];
    float C_0 = lC[d0], C_1 = lC[d1];
    float r2r0 = 1.0f / (2.0f * rv0), r2r1 = 1.0f / (2.0f * rv1);
    float pA0 = C_0 * C_0 * (Oo_0 + Om_0 * r2r0);
    float pB0 = Gm_0 - C_0 * C_0 * Om_0 * r2r0;
    float pA1 = C_1 * C_1 * (Oo_1 + Om_1 * r2r1);
    float pB1 = Gm_1 - C_1 * C_1 * Om_1 * r2r1;

    for (int s = tid; s < SQ; s += 512) t_lds[s] = tm[s];  // t_measure_all[0,:-1]
    __syncthreads();

    const fvec4* Kw4 = (const fvec4*)(ws + WK_OFF);
    const fvec4* Vw4 = (const fvec4*)(ws + WV_OFF);
    const fvec4* Qw4 = (const fvec4*)(ws + WQ_OFF);

    float ti = t_lds[i];
    fvec4 qb0 = Qw4[(size_t)(0 * SQ + i) * 32 + q];   // Q b0: [qr(d0),qi(d0),qr(d1),qi(d1)]
    fvec4 qb1 = Qw4[(size_t)(1 * SQ + i) * 32 + q];

    // accumulators: [batch][d-slot]
    float sA00 = 0, sA01 = 0, sXr00 = 0, sXr01 = 0, sXi00 = 0, sXi01 = 0;
    float sA10 = 0, sA11 = 0, sXr10 = 0, sXr11 = 0, sXi10 = 0, sXi11 = 0;

    float* xh0 = out + XHAT_OFF + (size_t)(0 * SQ + i) * SQ * 64;
    float* xh1 = out + XHAT_OFF + (size_t)(1 * SQ + i) * SQ * 64;
    float* xh2 = out + XHAT_OFF + (size_t)(2 * SQ + i) * SQ * 64;
    float* xh3 = out + XHAT_OFF + (size_t)(3 * SQ + i) * SQ * 64;
    float* qij0 = out + QIJ_OFF + (size_t)(0 * SQ + i) * SQ * 64;
    float* qij1 = out + QIJ_OFF + (size_t)(1 * SQ + i) * SQ * 64;

    #pragma unroll 2
    for (int j0 = 2 * wave; j0 <= i; j0 += 16) {
        int j = j0 + h2;
        if (j <= i) {
            float dt = ti - t_lds[j];
            float e_0 = __expf(rv0 * dt);
            float e_1 = __expf(rv1 * dt);
            float s_0, c_0, s_1, c_1;
            __sincosf(iv0 * dt, &s_0, &c_0);
            __sincosf(iv1 * dt, &s_1, &c_1);
            float ar0 = e_0 * c_0, ai0 = e_0 * s_0;
            float ar1 = e_1 * c_1, ai1 = e_1 * s_1;
            float P_0 = 1.0f / fmaf(e_0 * e_0, pA0, pB0);
            float P_1 = 1.0f / fmaf(e_1 * e_1, pA1, pB1);

            fvec4 k0 = Kw4[(size_t)(0 * SQ + j) * 32 + q];
            fvec4 v0 = Vw4[(size_t)(0 * SQ + j) * 32 + q];
            fvec4 k1 = Kw4[(size_t)(1 * SQ + j) * 32 + q];
            fvec4 v1 = Vw4[(size_t)(1 * SQ + j) * 32 + q];

            // batch0
            float xr00 = ar0 * v0[0] - ai0 * v0[1], xi00 = ar0 * v0[1] + ai0 * v0[0];
            float xr01 = ar1 * v0[2] - ai1 * v0[3], xi01 = ar1 * v0[3] + ai1 * v0[2];
            float kr00 = ar0 * k0[0] - ai0 * k0[1], ki00 = ar0 * k0[1] + ai0 * k0[0];
            float kr01 = ar1 * k0[2] - ai1 * k0[3], ki01 = ar1 * k0[3] + ai1 * k0[2];
            float Rr00 = qb0[0] - C_0 * kr00, Ri00 = qb0[1] - C_0 * ki00;
            float Rr01 = qb0[2] - C_1 * kr01, Ri01 = qb0[3] - C_1 * ki01;
            // batch1
            float xr10 = ar0 * v1[0] - ai0 * v1[1], xi10 = ar0 * v1[1] + ai0 * v1[0];
            float xr11 = ar1 * v1[2] - ai1 * v1[3], xi11 = ar1 * v1[3] + ai1 * v1[2];
            float kr10 = ar0 * k1[0] - ai0 * k1[1], ki10 = ar0 * k1[1] + ai0 * k1[0];
            float kr11 = ar1 * k1[2] - ai1 * k1[3], ki11 = ar1 * k1[3] + ai1 * k1[2];
            float Rr10 = qb1[0] - C_0 * kr10, Ri10 = qb1[1] - C_0 * ki10;
            float Rr11 = qb1[2] - C_1 * kr11, Ri11 = qb1[3] - C_1 * ki11;

            float m0 = P_0 * fmaf(Rr00, Rr00, Ri00 * Ri00) + P_1 * fmaf(Rr01, Rr01, Ri01 * Ri01);
            float m1 = P_0 * fmaf(Rr10, Rr10, Ri10 * Ri10) + P_1 * fmaf(Rr11, Rr11, Ri11 * Ri11);
            #pragma unroll
            for (int off = 16; off > 0; off >>= 1) {
                m0 += __shfl_xor(m0, off);
                m1 += __shfl_xor(m1, off);
            }
            float rdb0 = 1.0f / (1.0f + NU_C * m0);
            float rdb1 = 1.0f / (1.0f + NU_C * m1);
            float A00 = P_0 * rdb0, A01 = P_1 * rdb0;
            float A10 = P_0 * rdb1, A11 = P_1 * rdb1;
            sA00 += A00; sXr00 = fmaf(A00, xr00, sXr00); sXi00 = fmaf(A00, xi00, sXi00);
            sA01 += A01; sXr01 = fmaf(A01, xr01, sXr01); sXi01 = fmaf(A01, xi01, sXi01);
            sA10 += A10; sXr10 = fmaf(A10, xr10, sXr10); sXi10 = fmaf(A10, xi10, sXi10);
            sA11 += A11; sXr11 = fmaf(A11, xr11, sXr11); sXi11 = fmaf(A11, xi11, sXi11);

            size_t jb = (size_t)j * 64 + d0;
            fvec2 w0v = {xr00, xr01}; __builtin_nontemporal_store(w0v, (fvec2*)(xh0 + jb));
            fvec2 w1v = {xi00, xi01}; __builtin_nontemporal_store(w1v, (fvec2*)(xh1 + jb));
            fvec2 w2v = {xr10, xr11}; __builtin_nontemporal_store(w2v, (fvec2*)(xh2 + jb));
            fvec2 w3v = {xi10, xi11}; __builtin_nontemporal_store(w3v, (fvec2*)(xh3 + jb));
            if (q == 0) { rden_l[0][j] = rdb0; rden_l[1][j] = rdb1; }
        }
    }

    // combine the two halves (different j's, same d's)
    sA00 += __shfl_xor(sA00, 32); sXr00 += __shfl_xor(sXr00, 32); sXi00 += __shfl_xor(sXi00, 32);
    sA01 += __shfl_xor(sA01, 32); sXr01 += __shfl_xor(sXr01, 32); sXi01 += __shfl_xor(sXi01, 32);
    sA10 += __shfl_xor(sA10, 32); sXr10 += __shfl_xor(sXr10, 32); sXi10 += __shfl_xor(sXi10, 32);
    sA11 += __shfl_xor(sA11, 32); sXr11 += __shfl_xor(sXr11, 32); sXi11 += __shfl_xor(sXi11, 32);
    if (h2 == 0) {
        fvec2 a0 = {sA00, sA01};  *(fvec2*)&red[wave][0][0][d0] = a0;
        fvec2 x0 = {sXr00, sXr01}; *(fvec2*)&red[wave][0][1][d0] = x0;
        fvec2 y0 = {sXi00, sXi01}; *(fvec2*)&red[wave][0][2][d0] = y0;
        fvec2 a1 = {sA10, sA11};  *(fvec2*)&red[wave][1][0][d0] = a1;
        fvec2 x1 = {sXr10, sXr11}; *(fvec2*)&red[wave][1][1][d0] = x1;
        fvec2 y1 = {sXi10, sXi11}; *(fvec2*)&red[wave][1][2][d0] = y1;
    }
    __syncthreads();

    if (wave == 0) {
        int d = lane;
        float tA0 = 0, tXr0 = 0, tXi0 = 0, tA1 = 0, tXr1 = 0, tXi1 = 0;
        #pragma unroll
        for (int w = 0; w < 8; ++w) {
            tA0 += red[w][0][0][d]; tXr0 += red[w][0][1][d]; tXi0 += red[w][0][2][d];
            tA1 += red[w][1][0][d]; tXr1 += red[w][1][1][d]; tXi1 += red[w][1][2][d];
        }
        float rs0 = 1.0f / tA0, rs1 = 1.0f / tA1;
        rs_l[0][d] = rs0; rs_l[1][d] = rs1;
        float2 ev0; ev0.x = tXr0 * rs0; ev0.y = tXi0 * rs0;
        float2 ev1; ev1.x = tXr1 * rs1; ev1.y = tXi1 * rs1;
        *(float2*)&evw[(size_t)((0 * SQ + i) * 64 + d) * 2] = ev0;
        *(float2*)&evw[(size_t)((1 * SQ + i) * 64 + d) * 2] = ev1;
    }
    __syncthreads();

    float rs00 = rs_l[0][d0], rs01 = rs_l[0][d1];
    float rs10 = rs_l[1][d0], rs11 = rs_l[1][d1];

    // pass 2: Qij = P * rden * rsumA^-1
    #pragma unroll 2
    for (int j0 = 2 * wave; j0 <= i; j0 += 16) {
        int j = j0 + h2;
        if (j <= i) {
            float dt = ti - t_lds[j];
            float e2_0 = __expf(2.0f * rv0 * dt);
            float e2_1 = __expf(2.0f * rv1 * dt);
            float P_0 = 1.0f / fmaf(e2_0, pA0, pB0);
            float P_1 = 1.0f / fmaf(e2_1, pA1, pB1);
            float rdb0 = rden_l[0][j];
            float rdb1 = rden_l[1][j];
            size_t jb = (size_t)j * 64 + d0;
            fvec2 q0v = {P_0 * rdb0 * rs00, P_1 * rdb0 * rs01};
            fvec2 q1v = {P_0 * rdb1 * rs10, P_1 * rdb1 * rs11};
            __builtin_nontemporal_store(q0v, (fvec2*)(qij0 + jb));
            __builtin_nontemporal_store(q1v, (fvec2*)(qij1 + jb));
        }
    }

    // zero-fill masked region j in (i, S)
    int nz4 = ((SQ - 1 - i) * 64) >> 2;   // float4 count per region
    if (nz4 > 0) {
        fvec4 z = {0.f, 0.f, 0.f, 0.f};
        size_t zb = (size_t)(i + 1) * 64;
        float* regs[6] = {qij0 + zb, qij1 + zb, xh0 + zb, xh1 + zb, xh2 + zb, xh3 + zb};
        for (int r6 = 0; r6 < 6; ++r6) {
            float* p4 = regs[r6];
            for (int k4 = tid; k4 < nz4; k4 += 512)
                __builtin_nontemporal_store(z, (fvec4*)(p4 + (size_t)k4 * 4));
        }
    }
}

// ---------------------------------------------------------------------------
// Kernel 3: epilogue. est = cmm(We,be,est_v); pred = cmm(Wp,bp,rot(est_v));
// out = pred + est; lambda output. grid = 128: b x 64 s-tiles of 8.
// ---------------------------------------------------------------------------
__global__ __launch_bounds__(256) void epi_kernel(
    const float* __restrict__ tm,
    const float* __restrict__ lam1,
    const float* __restrict__ We, const float* __restrict__ be,
    const float* __restrict__ Wp, const float* __restrict__ bp,
    const float* __restrict__ evw,
    float* __restrict__ out)
{
    const int TILE = 8;
    __shared__ float WT0[64 * 65];
    __shared__ float WT1[64 * 65];
    __shared__ float EVr[TILE * 64];
    __shared__ float EVi[TILE * 64];
    __shared__ float mr_s[64], mi_s[64];

    int t = threadIdx.x;
    int blk = blockIdx.x;           // 128 blocks: 64 per batch
    int b = blk >> 6;
    int s0 = (blk & 63) * TILE;

    if (blk == 0 && t < 128) {      // lambda output (2,64)
        int dd = t & 63;
        float l0 = lam1[dd & 31];
        float l1 = lam1[32 + (dd & 31)];
        float v = (t < 64) ? -fabsf(l0) : ((dd < 32) ? l1 : -l1);
        out[LAM_OFF + t] = v;
    }
    if (t < 64) {                   // per-batch rotation
        int dd = t;
        float l0 = lam1[dd & 31];
        float l1 = lam1[32 + (dd & 31)];
        float realv = -fabsf(l0);
        float imagv = (dd < 32) ? l1 : -l1;
        float dtl = tm[b * (SQ + 1) + SQ] - tm[b * (SQ + 1) + SQ - 1];
        float e = __expf(realv * dtl);
        float s, c; __sincosf(imagv * dtl, &s, &c);
        mr_s[dd] = e * c; mi_s[dd] = e * s;
    }
    {   // stage est_v tile (contiguous [s][d][2])
        const float* src = evw + (size_t)(b * SQ + s0) * 128;
        for (int it = 0; it < (TILE * 128) / 256; ++it) {
            int e = it * 256 + t;
            float v = src[e];
            int sl = e >> 7, dd = (e >> 1) & 63, ri = e & 1;
            if (ri == 0) EVr[sl * 64 + dd] = v; else EVi[sl * 64 + dd] = v;
        }
    }
    for (int it = 0; it < 16; ++it) {   // stage We^T
        int e = it * 256 + t;
        int hw = e >> 6, dd = e & 63;
        WT0[dd * 65 + hw] = We[e];
        WT1[dd * 65 + hw] = We[4096 + e];
    }
    __syncthreads();

    int h = t & 63, sg = t >> 6;
    float estr[2], esti[2];
    float be0 = be[h], be1 = be[64 + h];
    #pragma unroll
    for (int k = 0; k < 2; ++k) {
        int sl = sg + k * 4;
        float ar = be0, ai = be1;
        for (int dd = 0; dd < 64; ++dd) {
            float er = EVr[sl * 64 + dd], ei = EVi[sl * 64 + dd];
            float w0 = WT0[dd * 65 + h], w1 = WT1[dd * 65 + h];
            ar += er * w0 - ei * w1;
            ai += er * w1 + ei * w0;
        }
        estr[k] = ar; esti[k] = ai;
        out[EST_OFF + (size_t)((b * 2 + 0) * SQ + s0 + sl) * 64 + h] = ar;
        out[EST_OFF + (size_t)((b * 2 + 1) * SQ + s0 + sl) * 64 + h] = ai;
    }
    __syncthreads();
    for (int it = 0; it < 16; ++it) {   // restage Wp^T
        int e = it * 256 + t;
        int hw = e >> 6, dd = e & 63;
        WT0[dd * 65 + hw] = Wp[e];
        WT1[dd * 65 + hw] = Wp[4096 + e];
    }
    __syncthreads();
    float bp0 = bp[h], bp1 = bp[64 + h];
    #pragma unroll
    for (int k = 0; k < 2; ++k) {
        int sl = sg + k * 4;
        float ar = bp0, ai = bp1;
        for (int dd = 0; dd < 64; ++dd) {
            float er = EVr[sl * 64 + dd], ei = EVi[sl * 64 + dd];
            float pr = mr_s[dd] * er - mi_s[dd] * ei;
            float pi = mr_s[dd] * ei + mi_s[dd] * er;
            float w0 = WT0[dd * 65 + h], w1 = WT1[dd * 65 + h];
            ar += pr * w0 - pi * w1;
            ai += pr * w1 + pi * w0;
        }
        out[OUT_OFF + (size_t)((b * 2 + 0) * SQ + s0 + sl) * 64 + h] = ar + estr[k];
        out[OUT_OFF + (size_t)((b * 2 + 1) * SQ + s0 + sl) * 64 + h] = ai + esti[k];
    }
}

// ---------------------------------------------------------------------------
extern "C" void kernel_launch(void* const* d_in, const int* in_sizes, int n_in,
                              void* d_out, int out_size, void* d_ws, size_t ws_size,
                              hipStream_t stream)
{
    const float* Xq   = (const float*)d_in[0];
    const float* Xk   = (const float*)d_in[1];
    const float* Xv   = (const float*)d_in[2];
    const float* tm   = (const float*)d_in[3];
    const float* lam1 = (const float*)d_in[4];
    const float* lOm  = (const float*)d_in[5];
    const float* lOm0 = (const float*)d_in[6];
    const float* lGam = (const float*)d_in[7];
    const float* lC   = (const float*)d_in[8];
    const float* Wq   = (const float*)d_in[9];
    const float* Wk   = (const float*)d_in[10];
    const float* Wv   = (const float*)d_in[11];
    const float* Wp   = (const float*)d_in[12];
    const float* We   = (const float*)d_in[13];
    const float* bq   = (const float*)d_in[14];
    const float* bk   = (const float*)d_in[15];
    const float* bv   = (const float*)d_in[16];
    const float* bp   = (const float*)d_in[17];
    const float* be   = (const float*)d_in[18];
    float* out = (float*)d_out;
    float* ws  = (float*)d_ws;

    proj_kernel<<<192, 256, 0, stream>>>(Xq, Xk, Xv, Wq, Wk, Wv, bq, bk, bv, ws);
    main_kernel<<<512, 512, 0, stream>>>(tm, lam1, lOm, lOm0, lGam, lC, ws, ws + WEV_OFF, out);
    epi_kernel<<<128, 256, 0, stream>>>(tm, lam1, We, be, Wp, bp, ws + WEV_OFF, out);
}